// Round 4
// baseline (302.097 us; speedup 1.0000x reference)
//
#include <hip/hip_runtime.h>
#include <hip/hip_bf16.h>

// Problem constants (B,S,D,H = 2,2048,2048,16 ; DPH = 128)
#define BB 2
#define HH 16
#define SS 2048
#define DD 2048
#define DPH_ 128
#define QBLK 64
#define KBLK 64
#define NT (SS / KBLK)   // 32

// LDS strides (bf16 elements); row strides must be 16B multiples for b128
#define KSTR 136   // kls [64 kv][KSTR]  272B = 17*16  ✓
#define VSTR 72    // vls [128 dph][VSTR] 144B = 9*16  ✓

typedef __bf16 bf16x8 __attribute__((ext_vector_type(8)));
typedef float f32x4 __attribute__((ext_vector_type(4)));
typedef float f32x16 __attribute__((ext_vector_type(16)));
typedef unsigned int u32x4 __attribute__((ext_vector_type(4)));

__device__ __forceinline__ unsigned f2bfbits(float f) {
  unsigned u = __builtin_bit_cast(unsigned, f);
  u += 0x7FFFu + ((u >> 16) & 1u);   // RNE
  return u >> 16;
}

// Swapped-operand fused flash attention. 4 waves = 2 qgrp x 2 kv-half.
// Per wave: S^T tile [32kv x 32q] (kv lane-local -> in-register softmax),
// partial O^T [128d x 32q] over its kv-half, epilogue split-kv merge.
// Also emits: raw scores (dot), prev_key/prev_value (exact fp32), mask.
__global__ __launch_bounds__(256, 3)
void attn_fused(const float* __restrict__ q, const int* __restrict__ maski,
                float* __restrict__ out, float* __restrict__ dot,
                float* __restrict__ pk, float* __restrict__ pv,
                float* __restrict__ omask) {
  __shared__ __align__(16) char smem[35840];   // kls+vls; reused as merge buf
  __shared__ float st[2][2][32][2];            // [qgrp][kvh][q][{m,l}]
  __bf16* kls = (__bf16*)smem;                 // [64][KSTR]   17408 B
  __bf16* vls = kls + KBLK * KSTR;             // [128][VSTR]  18432 B
  float* mrg = (float*)smem;                   // epilogue: [2][128d][32q] 32KB

  // XCD-bijective swizzle: 1024 blocks = 8 xcd x (32 qt x 4 (b,h)-groups)
  const int bid = blockIdx.x;
  const int xcd = bid & 7;
  const int idx = bid >> 3;          // 0..127
  const int qt  = idx & 31;
  const int G   = (idx >> 5) * 8 + xcd;  // 0..31 = b*16+h
  const int h   = G & 15;
  const int b   = G >> 4;

  const int tid  = threadIdx.x;
  const int wid  = tid >> 6;
  const int qgrp = wid & 1;          // 32-q group
  const int kvh  = wid >> 1;         // kv half (0..1)
  const int lane = tid & 63;
  const int c    = lane & 31;
  const int hl   = lane >> 5;

  // mask passthrough (block 0 only; disjoint from other outputs)
  if (bid == 0) {
    #pragma unroll
    for (int i = 0; i < 16; ++i)
      omask[tid + 256 * i] = (float)maski[tid + 256 * i];
  }

  const int qbase = qt * QBLK;
  const int qrow  = qbase + qgrp * 32 + c;
  const float scale = 0.08838834764831845f;   // 1/sqrt(128)
  const float* __restrict__ qh = q + (size_t)b * SS * DD + (size_t)h * DPH_;

  // ---- Q B-fragments in registers (col q = qrow, k = ks*16 + 8*hl + e) ----
  bf16x8 qB[8];
  {
    const float* qp = qh + (size_t)qrow * DD + 8 * hl;
    #pragma unroll
    for (int ks = 0; ks < 8; ++ks) {
      float4 a0 = *(const float4*)(qp + ks * 16);
      float4 a1 = *(const float4*)(qp + ks * 16 + 4);
      u32x4 t;
      t[0] = f2bfbits(a0.x) | (f2bfbits(a0.y) << 16);
      t[1] = f2bfbits(a0.z) | (f2bfbits(a0.w) << 16);
      t[2] = f2bfbits(a1.x) | (f2bfbits(a1.y) << 16);
      t[3] = f2bfbits(a1.z) | (f2bfbits(a1.w) << 16);
      qB[ks] = __builtin_bit_cast(bf16x8, t);
    }
  }

  // ---- staging ownership: row pair (2p2, 2p2+1), dph 16-chunk oo ----
  const int p2 = tid & 31;
  const int oo = tid >> 5;           // 0..7
  const int r0 = 2 * p2, r1 = r0 + 1;

  float4 f[8];                       // staged fp32 (rows r0:f[0..3], r1:f[4..7])
  unsigned kq[16];                   // bf16-packed (row-major)

  auto load_f = [&](int kvb) {
    const float* pA = qh + (size_t)(kvb + r0) * DD + 16 * oo;
    const float* pB = qh + (size_t)(kvb + r1) * DD + 16 * oo;
    #pragma unroll
    for (int i = 0; i < 4; ++i) {
      f[i]     = *(const float4*)(pA + 4 * i);
      f[4 + i] = *(const float4*)(pB + 4 * i);
    }
  };
  auto pkpv_store = [&](int kvb) {   // exact fp32 copies, [B,H,S,DPH]
    const size_t bh = (size_t)(b * HH + h);
    float* k0 = pk + (bh * SS + kvb + r0) * DPH_ + 16 * oo;
    float* k1 = pk + (bh * SS + kvb + r1) * DPH_ + 16 * oo;
    float* v0 = pv + (bh * SS + kvb + r0) * DPH_ + 16 * oo;
    float* v1 = pv + (bh * SS + kvb + r1) * DPH_ + 16 * oo;
    #pragma unroll
    for (int i = 0; i < 4; ++i) {
      *(float4*)(k0 + 4 * i) = f[i];   *(float4*)(k1 + 4 * i) = f[4 + i];
      *(float4*)(v0 + 4 * i) = f[i];   *(float4*)(v1 + 4 * i) = f[4 + i];
    }
  };
  auto convert_f = [&]() {
    #pragma unroll
    for (int i = 0; i < 4; ++i) {
      kq[2*i]     = f2bfbits(f[i].x)     | (f2bfbits(f[i].y) << 16);
      kq[2*i+1]   = f2bfbits(f[i].z)     | (f2bfbits(f[i].w) << 16);
      kq[8+2*i]   = f2bfbits(f[4+i].x)   | (f2bfbits(f[4+i].y) << 16);
      kq[8+2*i+1] = f2bfbits(f[4+i].z)   | (f2bfbits(f[4+i].w) << 16);
    }
  };
  auto write_kv = [&]() {
    u32x4 w0 = {kq[0], kq[1], kq[2],  kq[3]};
    u32x4 w1 = {kq[4], kq[5], kq[6],  kq[7]};
    u32x4 w2 = {kq[8], kq[9], kq[10], kq[11]};
    u32x4 w3 = {kq[12], kq[13], kq[14], kq[15]};
    *(u32x4*)(&kls[r0 * KSTR + 16 * oo])     = w0;
    *(u32x4*)(&kls[r0 * KSTR + 16 * oo + 8]) = w1;
    *(u32x4*)(&kls[r1 * KSTR + 16 * oo])     = w2;
    *(u32x4*)(&kls[r1 * KSTR + 16 * oo + 8]) = w3;
    // V^T: packed kv-pair b32 writes, conflict-free (bank = 4j + p2)
    #pragma unroll
    for (int j = 0; j < 16; ++j) {
      unsigned aA = (kq[j >> 1]     >> (16 * (j & 1))) & 0xFFFFu;
      unsigned aB = (kq[8 + (j >> 1)] >> (16 * (j & 1))) & 0xFFFFu;
      *(unsigned*)(&vls[(16 * oo + j) * VSTR + r0]) = aA | (aB << 16);
    }
  };

  f32x16 o16[4];
  #pragma unroll
  for (int dt = 0; dt < 4; ++dt)
    #pragma unroll
    for (int j = 0; j < 16; ++j) o16[dt][j] = 0.0f;
  float m = -1e30f, lsum = 0.0f;

  float* __restrict__ dotb = dot + ((size_t)(b * HH + h) << 22);  // S*S = 2^22

  // ---- prologue: stage tile 0 ----
  load_f(0);
  if (qt == 0) pkpv_store(0);
  convert_f();
  write_kv();
  __syncthreads();

  for (int kt = 0; kt < NT; ++kt) {
    const int kvbase = kt * KBLK;
    const int nxt = kvbase + KBLK;
    if (kt + 1 < NT) load_f(nxt);    // overlap next-tile HBM under compute

    // ---- QK^T swapped: S^T[kv][q], 8 MFMA 32x32x16 ----
    f32x16 s;
    #pragma unroll
    for (int j = 0; j < 16; ++j) s[j] = 0.0f;
    #pragma unroll
    for (int ks = 0; ks < 8; ++ks) {
      bf16x8 kf = *(const bf16x8*)(&kls[(kvh * 32 + c) * KSTR + ks * 16 + 8 * hl]);
      s = __builtin_amdgcn_mfma_f32_32x32x16_bf16(kf, qB[ks], s, 0, 0, 0);
    }
    s *= scale;

    // ---- raw scores -> dot[q][kv], f32x4 stores (L2 merges partial lines) --
    {
      float* dpb = dotb + (size_t)qrow * SS + kvbase + kvh * 32 + 4 * hl;
      #pragma unroll
      for (int rg = 0; rg < 4; ++rg) {
        f32x4 v = {s[4*rg], s[4*rg+1], s[4*rg+2], s[4*rg+3]};
        *(f32x4*)(dpb + 8 * rg) = v;
      }
    }

    if (kt + 1 < NT) {
      if (kt + 1 == qt) pkpv_store(nxt);  // exact fp32 before conversion
      convert_f();                        // fp32 staging regs die here
    }

    // ---- online softmax, kv lane-local (T13 defer-max, THR=8) ----
    float mx = s[0];
    #pragma unroll
    for (int j = 1; j < 16; ++j) mx = fmaxf(mx, s[j]);
    mx = fmaxf(mx, __shfl_xor(mx, 32));
    if (!__all(mx - m <= 8.0f)) {
      float mn = fmaxf(m, mx);
      float al = __expf(m - mn);
      lsum *= al;
      #pragma unroll
      for (int dt = 0; dt < 4; ++dt) o16[dt] *= al;
      m = mn;
    }
    float p[16];
    float sum = 0.0f;
    #pragma unroll
    for (int j = 0; j < 16; ++j) { p[j] = __expf(s[j] - m); sum += p[j]; }
    sum += __shfl_xor(sum, 32);
    lsum += sum;

    // ---- P -> bf16 B-frags in-register (pack + half-wave exchange) ----
    unsigned X[8];
    #pragma unroll
    for (int i = 0; i < 8; ++i)
      X[i] = f2bfbits(p[2*i]) | (f2bfbits(p[2*i+1]) << 16);
    bf16x8 pf[2];
    #pragma unroll
    for (int ks = 0; ks < 2; ++ks) {
      unsigned XA = X[4*ks], XB = X[4*ks+1], XC = X[4*ks+2], XD = X[4*ks+3];
      unsigned sA = __shfl_xor(XA, 32), sB = __shfl_xor(XB, 32);
      unsigned sC = __shfl_xor(XC, 32), sD = __shfl_xor(XD, 32);
      u32x4 dd;
      dd[0] = hl ? sC : XA;
      dd[1] = hl ? sD : XB;
      dd[2] = hl ? XC : sA;
      dd[3] = hl ? XD : sB;
      pf[ks] = __builtin_bit_cast(bf16x8, dd);
    }

    // ---- PV: O^T += V^T * P^T over this wave's kv-half (8 MFMA) ----
    #pragma unroll
    for (int ks = 0; ks < 2; ++ks) {
      #pragma unroll
      for (int dt = 0; dt < 4; ++dt) {
        bf16x8 vf = *(const bf16x8*)(&vls[(dt * 32 + c) * VSTR + kvh * 32 + ks * 16 + 8 * hl]);
        o16[dt] = __builtin_amdgcn_mfma_f32_32x32x16_bf16(vf, pf[ks], o16[dt], 0, 0, 0);
      }
    }

    __syncthreads();                     // all waves done reading kls/vls
    if (kt + 1 < NT) write_kv();         // stage tile kt+1
    __syncthreads();
  }

  // ---- epilogue: split-kv merge across wave pairs, then store out ----
  if (hl == 0) { st[qgrp][kvh][c][0] = m; st[qgrp][kvh][c][1] = lsum; }
  __syncthreads();
  const float pm = st[qgrp][kvh ^ 1][c][0];
  const float pl = st[qgrp][kvh ^ 1][c][1];
  const float M  = fmaxf(m, pm);
  const float w  = __expf(m - M);
  const float wp = __expf(pm - M);

  if (kvh == 1) {
    #pragma unroll
    for (int dt = 0; dt < 4; ++dt)
      #pragma unroll
      for (int r = 0; r < 16; ++r) {
        int d = dt * 32 + (r & 3) + 8 * (r >> 2) + 4 * hl;
        mrg[qgrp * 4096 + d * 32 + c] = o16[dt][r] * w;
      }
  }
  __syncthreads();
  if (kvh == 0) {
    const float L = lsum * w + pl * wp;
    const float invL = 1.0f / L;
    float* ob = out + ((size_t)b * SS + qrow) * DD + h * DPH_;
    #pragma unroll
    for (int dt = 0; dt < 4; ++dt)
      #pragma unroll
      for (int rg = 0; rg < 4; ++rg) {
        f32x4 v;
        #pragma unroll
        for (int j = 0; j < 4; ++j) {
          int d = dt * 32 + j + 8 * rg + 4 * hl;
          v[j] = (o16[dt][4*rg + j] * w + mrg[qgrp * 4096 + d * 32 + c]) * invL;
        }
        *(f32x4*)(ob + dt * 32 + 8 * rg + 4 * hl) = v;
      }
  }
}

extern "C" void kernel_launch(void* const* d_in, const int* in_sizes, int n_in,
                              void* d_out, int out_size, void* d_ws, size_t ws_size,
                              hipStream_t stream) {
  const float* q    = (const float*)d_in[0];
  const int*   mask = (const int*)d_in[1];
  float* out = (float*)d_out;

  // Output layout (concatenated flat, fp32):
  float* o_out  = out;                 // [B,S,D]        8,388,608
  float* o_pk   = out + 8388608;       // [B,H,S,DPH]    8,388,608
  float* o_pv   = out + 16777216;      // [B,H,S,DPH]    8,388,608
  float* o_mask = out + 25165824;      // [B,S]              4,096
  float* o_dot  = out + 25169920;      // [B*H,S,S]    134,217,728

  // 1024 blocks = 32 qt x 16 h x 2 b, XCD-swizzled in-kernel
  attn_fused<<<dim3(1024), dim3(256), 0, stream>>>(
      q, mask, o_out, o_dot, o_pk, o_pv, o_mask);
}